// Round 2
// baseline (10430.156 us; speedup 1.0000x reference)
//
#include <hip/hip_runtime.h>
#include <hip/hip_bf16.h>

#define CIN 384
#define PQ 1024
#define PKV 256
#define HEADS 6
#define DH 64
#define INNER 384
#define ATTN_SCALE 0.125f

typedef __hip_bfloat16 bf16;

__device__ __forceinline__ float b2f(bf16 v) { return __bfloat162float(v); }
__device__ __forceinline__ bf16 f2b(float v) { return __float2bfloat16(v); }
// dtype-flexible input load: isbf ? bf16[i] : float[i]
__device__ __forceinline__ float ldf(const void* p, size_t i, int isbf) {
    return isbf ? __bfloat162float(((const bf16*)p)[i]) : ((const float*)p)[i];
}

// ---------------- input dtype probe ----------------------------------------------
// bf16 data: low 16 bits of each u32 word are a bf16 of ~N(0,1) -> exp in [100,140].
// fp32 data: those bits are low mantissa bits -> uniform -> ~16% in range.
__global__ void detect_kernel(const unsigned int* __restrict__ x, int* __restrict__ flag) {
    if (threadIdx.x == 0 && blockIdx.x == 0) {
        int cnt = 0;
        for (int i = 0; i < 64; i++) {
            unsigned int e = (x[i] >> 7) & 0xFFu;
            if (e >= 100u && e <= 140u) cnt++;
        }
        *flag = (cnt >= 48) ? 1 : 0;
    }
}

// ---------------- depthwise 3x3 + BN (fused), one block per (b,c) plane ----------
template <int STRIDE, int HO, int WO>
__global__ void dw_bn_kernel(const void* __restrict__ x, const void* __restrict__ wdw,
                             const void* __restrict__ gamma, const void* __restrict__ beta,
                             const void* __restrict__ mean, const void* __restrict__ var,
                             bf16* __restrict__ y, const int* __restrict__ flagp) {
    __shared__ float xs[32][33];
    int isbf = *flagp;
    int bc = blockIdx.x;
    int c = bc % CIN;
    int tid = threadIdx.x;
    size_t xbase = (size_t)bc * (32 * 32);
    for (int i = tid; i < 32 * 32; i += 256)
        xs[i >> 5][i & 31] = ldf(x, xbase + i, isbf);
    float w[9];
#pragma unroll
    for (int k = 0; k < 9; k++) w[k] = ldf(wdw, c * 9 + k, isbf);
    float inv = ldf(gamma, c, isbf) * rsqrtf(ldf(var, c, isbf) + 1e-5f);
    float bias = ldf(beta, c, isbf) - ldf(mean, c, isbf) * inv;
    __syncthreads();
    for (int p = tid; p < HO * WO; p += 256) {
        int ho = p / WO, wo = p % WO;
        int ci = ho * STRIDE, cj = wo * STRIDE;
        float acc = 0.f;
#pragma unroll
        for (int ky = 0; ky < 3; ky++) {
            int yy = ci + ky - 1;
            if (yy < 0 || yy >= 32) continue;
#pragma unroll
            for (int kx = 0; kx < 3; kx++) {
                int xx = cj + kx - 1;
                if (xx < 0 || xx >= 32) continue;
                acc += w[ky * 3 + kx] * xs[yy][xx];
            }
        }
        y[(size_t)bc * (HO * WO) + p] = f2b(acc * inv + bias);
    }
}

// ---------------- 1x1 conv as per-batch GEMM: out[o][p] = sum_c w[o][c]*y[c][p] ----
// 64x64 tile, 256 threads, 4x4 microtile, fp32 accumulation. W/bias are INPUTS
// (dtype-flexible); y is always bf16 workspace. Final store branches on dtype.
template <int P>
__global__ void pw_gemm_kernel(const void* __restrict__ w, const bf16* __restrict__ y,
                               const void* __restrict__ bias, void* __restrict__ out,
                               int O, const int* __restrict__ flagp, int is_final) {
    __shared__ float Wt[16][64];
    __shared__ float Yt[16][64];
    int isbf = *flagp;
    int b = blockIdx.z;
    int o0 = blockIdx.y * 64;
    int p0 = blockIdx.x * 64;
    const bf16* yb = y + (size_t)b * CIN * P;
    int tid = threadIdx.x;
    int tr = tid >> 4, tc = tid & 15;
    int i0 = tr * 4, j0 = tc * 4;
    float acc[4][4] = {};
    int l0 = tid * 4;
    int wi = l0 >> 4, wk = l0 & 15;  // W tile: row wi, k = wk..wk+3
    int yk = l0 >> 6, yj = l0 & 63;  // Y tile: k = yk, col yj..yj+3

    for (int kc = 0; kc < CIN; kc += 16) {
        size_t wbase = (size_t)(o0 + wi) * CIN + kc + wk;
        const bf16* yp = yb + (size_t)(kc + yk) * P + p0 + yj;
#pragma unroll
        for (int u = 0; u < 4; u++) Wt[wk + u][wi] = ldf(w, wbase + u, isbf);
#pragma unroll
        for (int u = 0; u < 4; u++) Yt[yk][yj + u] = b2f(yp[u]);
        __syncthreads();
#pragma unroll
        for (int kk = 0; kk < 16; kk++) {
            float4 av = *(const float4*)&Wt[kk][i0];
            float4 bv = *(const float4*)&Yt[kk][j0];
            float a[4] = {av.x, av.y, av.z, av.w};
            float bb[4] = {bv.x, bv.y, bv.z, bv.w};
#pragma unroll
            for (int r = 0; r < 4; r++)
#pragma unroll
                for (int cc = 0; cc < 4; cc++) acc[r][cc] += a[r] * bb[cc];
        }
        __syncthreads();
    }
#pragma unroll
    for (int r = 0; r < 4; r++) {
        float bv = bias ? ldf(bias, o0 + i0 + r, isbf) : 0.f;
        size_t obase = (size_t)b * O * P + (size_t)(o0 + i0 + r) * P + p0 + j0;
#pragma unroll
        for (int cc = 0; cc < 4; cc++) {
            float v = acc[r][cc] + bv;
            if (is_final && !isbf) ((float*)out)[obase + cc] = v;
            else                   ((bf16*)out)[obase + cc] = f2b(v);
        }
    }
}

// ---------------- fused attention ------------------------------------------------
// One block (256 thr = 4 waves) handles 16 q-rows of one (b,head). Each wave: 4 rows.
// K/V streamed through LDS in 4 chunks of 64 columns. Softmax fully in-wave.
__global__ void attn_kernel(const bf16* __restrict__ q, const bf16* __restrict__ kv,
                            bf16* __restrict__ ao) {
    __shared__ float qs[16][64];    // 16 rows x 64 dims (pre-scaled)
    __shared__ float kvs[64][68];   // K chunk as [j'][d]; V chunk as [d][j']
    __shared__ float ps[16][260];   // softmax probabilities
    int blk = blockIdx.x;
    int b = blk / (HEADS * 64);
    int rem = blk % (HEADS * 64);
    int head = rem / 64;
    int p0 = (rem % 64) * 16;
    int tid = threadIdx.x;
    int wave = tid >> 6, lane = tid & 63;

    const bf16* qb = q + ((size_t)b * INNER + head * DH) * PQ;
    for (int l = tid; l < 16 * 64; l += 256) {
        int rrg = l & 15, d = l >> 4;
        qs[rrg][d] = b2f(qb[(size_t)d * PQ + p0 + rrg]) * ATTN_SCALE;
    }
    __syncthreads();

    const bf16* kb = kv + ((size_t)b * 2 * INNER + head * DH) * PKV;
    const bf16* vb = kv + ((size_t)b * 2 * INNER + INNER + head * DH) * PKV;

    float dots[4][4];  // [row][chunk], j = chunk*64 + lane
#pragma unroll
    for (int r = 0; r < 4; r++)
#pragma unroll
        for (int jc = 0; jc < 4; jc++) dots[r][jc] = 0.f;

#pragma unroll
    for (int jc = 0; jc < 4; jc++) {
        for (int l = tid; l < 4096; l += 256) {
            int d = l >> 6, jp = l & 63;
            kvs[jp][d] = b2f(kb[(size_t)d * PKV + jc * 64 + jp]);
        }
        __syncthreads();
#pragma unroll
        for (int dd = 0; dd < 64; dd += 4) {
            float4 kvec = *(const float4*)&kvs[lane][dd];
#pragma unroll
            for (int r = 0; r < 4; r++) {
                float4 qv = *(const float4*)&qs[wave * 4 + r][dd];
                dots[r][jc] += qv.x * kvec.x + qv.y * kvec.y + qv.z * kvec.z + qv.w * kvec.w;
            }
        }
        __syncthreads();
    }

    float outv[4];
#pragma unroll
    for (int r = 0; r < 4; r++) {
        float m = fmaxf(fmaxf(dots[r][0], dots[r][1]), fmaxf(dots[r][2], dots[r][3]));
#pragma unroll
        for (int off = 32; off > 0; off >>= 1) m = fmaxf(m, __shfl_xor(m, off, 64));
        float e[4], s = 0.f;
#pragma unroll
        for (int jc = 0; jc < 4; jc++) { e[jc] = __expf(dots[r][jc] - m); s += e[jc]; }
#pragma unroll
        for (int off = 32; off > 0; off >>= 1) s += __shfl_xor(s, off, 64);
        float is = 1.f / s;
#pragma unroll
        for (int jc = 0; jc < 4; jc++) ps[wave * 4 + r][jc * 64 + lane] = e[jc] * is;
        outv[r] = 0.f;
    }
    __syncthreads();

#pragma unroll
    for (int jc = 0; jc < 4; jc++) {
        for (int l = tid; l < 4096; l += 256) {
            int d = l >> 6, jp = l & 63;
            kvs[d][jp] = b2f(vb[(size_t)d * PKV + jc * 64 + jp]);  // V transposed: [d][j']
        }
        __syncthreads();
#pragma unroll
        for (int jj = 0; jj < 64; jj += 4) {
            float4 vv = *(const float4*)&kvs[lane][jj];  // lane = d
#pragma unroll
            for (int r = 0; r < 4; r++) {
                float4 pv = *(const float4*)&ps[wave * 4 + r][jc * 64 + jj];
                outv[r] += pv.x * vv.x + pv.y * vv.y + pv.z * vv.z + pv.w * vv.w;
            }
        }
        __syncthreads();
    }

    bf16* aob = ao + ((size_t)b * INNER + head * DH) * PQ;
#pragma unroll
    for (int r = 0; r < 4; r++)
        aob[(size_t)lane * PQ + p0 + wave * 4 + r] = f2b(outv[r]);
}

extern "C" void kernel_launch(void* const* d_in, const int* in_sizes, int n_in,
                              void* d_out, int out_size, void* d_ws, size_t ws_size,
                              hipStream_t stream) {
    const void* x       = d_in[0];
    const void* q_dw    = d_in[1];
    const void* q_gamma = d_in[2];
    const void* q_beta  = d_in[3];
    const void* q_mean  = d_in[4];
    const void* q_var   = d_in[5];
    const void* q_pw    = d_in[6];
    const void* kv_dw   = d_in[7];
    const void* kv_gamma= d_in[8];
    const void* kv_beta = d_in[9];
    const void* kv_mean = d_in[10];
    const void* kv_var  = d_in[11];
    const void* kv_pw   = d_in[12];
    const void* out_w   = d_in[13];
    const void* out_b   = d_in[14];

    int* flag = (int*)d_ws;
    bf16* pool = (bf16*)((char*)d_ws + 256);
    bf16* yq  = pool;                           // [32,384,1024]  (reused as aob later)
    bf16* ykv = yq  + (size_t)32 * 384 * 1024;  // [32,384,256]
    bf16* qb  = ykv + (size_t)32 * 384 * 256;   // [32,384,1024]
    bf16* kvb = qb  + (size_t)32 * 384 * 1024;  // [32,768,256]
    bf16* aob = yq;                             // alias: yq is dead after pw_gemm #1

    detect_kernel<<<1, 64, 0, stream>>>((const unsigned int*)x, flag);
    dw_bn_kernel<1, 32, 32><<<32 * 384, 256, 0, stream>>>(x, q_dw, q_gamma, q_beta, q_mean, q_var, yq, flag);
    dw_bn_kernel<2, 16, 16><<<32 * 384, 256, 0, stream>>>(x, kv_dw, kv_gamma, kv_beta, kv_mean, kv_var, ykv, flag);
    pw_gemm_kernel<1024><<<dim3(16, 6, 32), 256, 0, stream>>>(q_pw, yq, nullptr, qb, 384, flag, 0);
    pw_gemm_kernel<256><<<dim3(4, 12, 32), 256, 0, stream>>>(kv_pw, ykv, nullptr, kvb, 768, flag, 0);
    attn_kernel<<<32 * 6 * 64, 256, 0, stream>>>(qb, kvb, aob);
    pw_gemm_kernel<1024><<<dim3(16, 6, 32), 256, 0, stream>>>(out_w, aob, out_b, d_out, 384, flag, 1);
}

// Round 3
// 713.142 us; speedup vs baseline: 14.6256x; 14.6256x over previous
//
#include <hip/hip_runtime.h>
#include <hip/hip_bf16.h>

#define CIN 384
#define PQ 1024
#define PKV 256
#define HEADS 6
#define DH 64
#define INNER 384
#define ATTN_SCALE 0.125f

typedef __hip_bfloat16 bf16;
typedef unsigned short ushort;
typedef __bf16 bf16x8 __attribute__((ext_vector_type(8)));
typedef float floatx4 __attribute__((ext_vector_type(4)));

__device__ __forceinline__ float b2f(bf16 v) { return __bfloat162float(v); }
__device__ __forceinline__ bf16 f2b(float v) { return __float2bfloat16(v); }
__device__ __forceinline__ ushort f2bu(float v) { bf16 h = __float2bfloat16(v); return *(ushort*)&h; }
// dtype-flexible input load: isbf ? bf16[i] : float[i]
__device__ __forceinline__ float ldf(const void* p, size_t i, int isbf) {
    return isbf ? __bfloat162float(((const bf16*)p)[i]) : ((const float*)p)[i];
}

// ---------------- input dtype probe ----------------------------------------------
__global__ void detect_kernel(const unsigned int* __restrict__ x, int* __restrict__ flag) {
    if (threadIdx.x == 0 && blockIdx.x == 0) {
        int cnt = 0;
        for (int i = 0; i < 64; i++) {
            unsigned int e = (x[i] >> 7) & 0xFFu;
            if (e >= 100u && e <= 140u) cnt++;
        }
        *flag = (cnt >= 48) ? 1 : 0;
    }
}

// ---------------- depthwise 3x3 + BN (fused), one block per (b,c) plane ----------
template <int STRIDE, int HO, int WO>
__global__ void dw_bn_kernel(const void* __restrict__ x, const void* __restrict__ wdw,
                             const void* __restrict__ gamma, const void* __restrict__ beta,
                             const void* __restrict__ mean, const void* __restrict__ var,
                             bf16* __restrict__ y, const int* __restrict__ flagp) {
    __shared__ float xs[32][33];
    int isbf = *flagp;
    int bc = blockIdx.x;
    int c = bc % CIN;
    int tid = threadIdx.x;
    size_t xbase = (size_t)bc * (32 * 32);
    for (int i = tid; i < 32 * 32; i += 256)
        xs[i >> 5][i & 31] = ldf(x, xbase + i, isbf);
    float w[9];
#pragma unroll
    for (int k = 0; k < 9; k++) w[k] = ldf(wdw, c * 9 + k, isbf);
    float inv = ldf(gamma, c, isbf) * rsqrtf(ldf(var, c, isbf) + 1e-5f);
    float bias = ldf(beta, c, isbf) - ldf(mean, c, isbf) * inv;
    __syncthreads();
    for (int p = tid; p < HO * WO; p += 256) {
        int ho = p / WO, wo = p % WO;
        int ci = ho * STRIDE, cj = wo * STRIDE;
        float acc = 0.f;
#pragma unroll
        for (int ky = 0; ky < 3; ky++) {
            int yy = ci + ky - 1;
            if (yy < 0 || yy >= 32) continue;
#pragma unroll
            for (int kx = 0; kx < 3; kx++) {
                int xx = cj + kx - 1;
                if (xx < 0 || xx >= 32) continue;
                acc += w[ky * 3 + kx] * xs[yy][xx];
            }
        }
        y[(size_t)bc * (HO * WO) + p] = f2b(acc * inv + bias);
    }
}

// ---------------- 1x1 conv as per-batch GEMM ----------------------------------
// out[o][p] = sum_c w[w_off + o*CIN + c] * y[c][p]
// mode 0: out bf16 [b][O][P]
// mode 1: out bf16 [(b*6 + o/64)][P][64] (per-head row-major, for MFMA frags)
// mode 2: final output [b][O][P], dtype per isbf flag
template <int P>
__global__ void pw_gemm_kernel(const void* __restrict__ w, size_t w_off,
                               const bf16* __restrict__ y,
                               const void* __restrict__ bias, void* __restrict__ out,
                               int O, const int* __restrict__ flagp, int mode) {
    __shared__ float Wt[16][64];
    __shared__ float Yt[16][64];
    int isbf = *flagp;
    int b = blockIdx.z;
    int o0 = blockIdx.y * 64;
    int p0 = blockIdx.x * 64;
    const bf16* yb = y + (size_t)b * CIN * P;
    int tid = threadIdx.x;
    int tr = tid >> 4, tc = tid & 15;
    int i0 = tr * 4, j0 = tc * 4;
    float acc[4][4] = {};
    int l0 = tid * 4;
    int wi = l0 >> 4, wk = l0 & 15;
    int yk = l0 >> 6, yj = l0 & 63;

    for (int kc = 0; kc < CIN; kc += 16) {
        size_t wbase = w_off + (size_t)(o0 + wi) * CIN + kc + wk;
        const bf16* yp = yb + (size_t)(kc + yk) * P + p0 + yj;
#pragma unroll
        for (int u = 0; u < 4; u++) Wt[wk + u][wi] = ldf(w, wbase + u, isbf);
#pragma unroll
        for (int u = 0; u < 4; u++) Yt[yk][yj + u] = b2f(yp[u]);
        __syncthreads();
#pragma unroll
        for (int kk = 0; kk < 16; kk++) {
            float4 av = *(const float4*)&Wt[kk][i0];
            float4 bv = *(const float4*)&Yt[kk][j0];
            float a[4] = {av.x, av.y, av.z, av.w};
            float bb[4] = {bv.x, bv.y, bv.z, bv.w};
#pragma unroll
            for (int r = 0; r < 4; r++)
#pragma unroll
                for (int cc = 0; cc < 4; cc++) acc[r][cc] += a[r] * bb[cc];
        }
        __syncthreads();
    }
#pragma unroll
    for (int r = 0; r < 4; r++) {
        int o = o0 + i0 + r;
        float bv = bias ? ldf(bias, o, isbf) : 0.f;
#pragma unroll
        for (int cc = 0; cc < 4; cc++) {
            float v = acc[r][cc] + bv;
            int p = p0 + j0 + cc;
            if (mode == 1) {
                ((bf16*)out)[((size_t)(b * HEADS + (o >> 6)) * P + p) * 64 + (o & 63)] = f2b(v);
            } else {
                size_t idx = (size_t)b * O * P + (size_t)o * P + p;
                if (mode == 2 && !isbf) ((float*)out)[idx] = v;
                else                    ((bf16*)out)[idx] = f2b(v);
            }
        }
    }
}

// ---------------- fused MFMA attention -------------------------------------------
// Block = 4 waves; wave handles 16 q-rows vs all 256 kv-cols of one (b,head).
// q: [b,h,p,64]  k: [b,h,j,64]  v: [b, h*64+d, j]  out: [b, h*64+d, p]
__global__ void attn_kernel(const bf16* __restrict__ qalt, const bf16* __restrict__ kalt,
                            const bf16* __restrict__ valt, bf16* __restrict__ ao) {
    __shared__ __align__(16) ushort Pl[4][16][264];  // P, padded (264) for bank spread
    int tid = threadIdx.x;
    int wave = tid >> 6, lane = tid & 63;
    int l15 = lane & 15, quad = lane >> 4;
    int blk = blockIdx.x;
    int b = blk / (HEADS * 16);
    int rem = blk % (HEADS * 16);
    int h = rem / 16;
    int p0 = (rem % 16) * 64 + wave * 16;

    const bf16* qbase = qalt + (size_t)(b * HEADS + h) * PQ * DH;
    const bf16* kbase = kalt + (size_t)(b * HEADS + h) * PKV * DH;
    const bf16* vbase = valt + ((size_t)b * INNER + h * DH) * PKV;

    // A-frags of Q: A[m=l15][k=quad*8+j], two k-steps (0,32)
    const bf16* qrow = qbase + (size_t)(p0 + l15) * DH + quad * 8;
    bf16x8 a0 = *(const bf16x8*)qrow;
    bf16x8 a1 = *(const bf16x8*)(qrow + 32);

    // S = Q K^T : 16 j-tiles of 16 cols
    floatx4 s[16];
#pragma unroll
    for (int jt = 0; jt < 16; jt++) s[jt] = (floatx4){0.f, 0.f, 0.f, 0.f};
#pragma unroll
    for (int jt = 0; jt < 16; jt++) {
        const bf16* krow = kbase + (size_t)(jt * 16 + l15) * DH + quad * 8;
        bf16x8 b0 = *(const bf16x8*)krow;
        bf16x8 b1 = *(const bf16x8*)(krow + 32);
        s[jt] = __builtin_amdgcn_mfma_f32_16x16x32_bf16(a0, b0, s[jt], 0, 0, 0);
        s[jt] = __builtin_amdgcn_mfma_f32_16x16x32_bf16(a1, b1, s[jt], 0, 0, 0);
    }

    // softmax over rows (row = quad*4+r lives in the 16 lanes sharing `quad`)
#pragma unroll
    for (int r = 0; r < 4; r++) {
        float mx = s[0][r];
#pragma unroll
        for (int jt = 1; jt < 16; jt++) mx = fmaxf(mx, s[jt][r]);
#pragma unroll
        for (int off = 1; off <= 8; off <<= 1) mx = fmaxf(mx, __shfl_xor(mx, off, 64));
        float sm = 0.f;
#pragma unroll
        for (int jt = 0; jt < 16; jt++) {
            float e = __expf((s[jt][r] - mx) * ATTN_SCALE);
            s[jt][r] = e;
            sm += e;
        }
#pragma unroll
        for (int off = 1; off <= 8; off <<= 1) sm += __shfl_xor(sm, off, 64);
        float inv = 1.f / sm;
#pragma unroll
        for (int jt = 0; jt < 16; jt++)
            Pl[wave][quad * 4 + r][jt * 16 + l15] = f2bu(s[jt][r] * inv);
    }
    __syncthreads();  // C-layout -> A-layout transform visibility (cross-lane via LDS)

    // O = P V : 4 n-tiles (d), 8 k-steps (j)
    floatx4 oacc[4];
#pragma unroll
    for (int nt = 0; nt < 4; nt++) oacc[nt] = (floatx4){0.f, 0.f, 0.f, 0.f};
    bf16x8 pa[8];
#pragma unroll
    for (int kk = 0; kk < 8; kk++)
        pa[kk] = *(const bf16x8*)&Pl[wave][l15][kk * 32 + quad * 8];
#pragma unroll
    for (int nt = 0; nt < 4; nt++) {
#pragma unroll
        for (int kk = 0; kk < 8; kk++) {
            const bf16* vrow = vbase + (size_t)(nt * 16 + l15) * PKV + kk * 32 + quad * 8;
            bf16x8 bv = *(const bf16x8*)vrow;
            oacc[nt] = __builtin_amdgcn_mfma_f32_16x16x32_bf16(pa[kk], bv, oacc[nt], 0, 0, 0);
        }
    }

    // store: C row = q-row p, col = d. Write [b, h*64+d, p] with 4 consecutive p packed.
    bf16* aob = ao + ((size_t)b * INNER + h * DH) * PQ;
#pragma unroll
    for (int nt = 0; nt < 4; nt++) {
        ushort4 o4;
        o4.x = f2bu(oacc[nt][0]);
        o4.y = f2bu(oacc[nt][1]);
        o4.z = f2bu(oacc[nt][2]);
        o4.w = f2bu(oacc[nt][3]);
        *(ushort4*)(aob + (size_t)(nt * 16 + l15) * PQ + p0 + quad * 4) = o4;
    }
}

extern "C" void kernel_launch(void* const* d_in, const int* in_sizes, int n_in,
                              void* d_out, int out_size, void* d_ws, size_t ws_size,
                              hipStream_t stream) {
    const void* x        = d_in[0];
    const void* q_dw     = d_in[1];
    const void* q_gamma  = d_in[2];
    const void* q_beta   = d_in[3];
    const void* q_mean   = d_in[4];
    const void* q_var    = d_in[5];
    const void* q_pw     = d_in[6];
    const void* kv_dw    = d_in[7];
    const void* kv_gamma = d_in[8];
    const void* kv_beta  = d_in[9];
    const void* kv_mean  = d_in[10];
    const void* kv_var   = d_in[11];
    const void* kv_pw    = d_in[12];
    const void* out_w    = d_in[13];
    const void* out_b    = d_in[14];

    int* flag = (int*)d_ws;
    bf16* pool = (bf16*)((char*)d_ws + 256);
    bf16* yq   = pool;                            // [32,384,1024] ; reused as aob
    bf16* ykv  = yq   + (size_t)32 * 384 * 1024;  // [32,384,256]
    bf16* qalt = ykv  + (size_t)32 * 384 * 256;   // [32,6,1024,64]
    bf16* kalt = qalt + (size_t)32 * 384 * 1024;  // [32,6,256,64]
    bf16* valt = kalt + (size_t)32 * 6 * 256 * 64;// [32,384,256]
    bf16* aob  = yq;                              // alias: yq dead after Q pointwise

    detect_kernel<<<1, 64, 0, stream>>>((const unsigned int*)x, flag);
    dw_bn_kernel<1, 32, 32><<<32 * 384, 256, 0, stream>>>(x, q_dw, q_gamma, q_beta, q_mean, q_var, yq, flag);
    dw_bn_kernel<2, 16, 16><<<32 * 384, 256, 0, stream>>>(x, kv_dw, kv_gamma, kv_beta, kv_mean, kv_var, ykv, flag);
    pw_gemm_kernel<1024><<<dim3(16, 6, 32), 256, 0, stream>>>(q_pw, 0, yq, nullptr, qalt, INNER, flag, 1);
    pw_gemm_kernel<256><<<dim3(4, 6, 32), 256, 0, stream>>>(kv_pw, 0, ykv, nullptr, kalt, INNER, flag, 1);
    pw_gemm_kernel<256><<<dim3(4, 6, 32), 256, 0, stream>>>(kv_pw, (size_t)INNER * CIN, ykv, nullptr, valt, INNER, flag, 0);
    attn_kernel<<<32 * 6 * 16, 256, 0, stream>>>(qalt, kalt, valt, aob);
    pw_gemm_kernel<1024><<<dim3(16, 6, 32), 256, 0, stream>>>(out_w, 0, aob, out_b, d_out, CIN, flag, 2);
}

// Round 5
// 450.534 us; speedup vs baseline: 23.1506x; 1.5829x over previous
//
#include <hip/hip_runtime.h>
#include <hip/hip_bf16.h>

#define CIN 384
#define PQ 1024
#define PKV 256
#define HEADS 6
#define DH 64
#define INNER 384
#define ATTN_SCALE 0.125f

typedef __hip_bfloat16 bf16;
typedef unsigned short ushort;
typedef __bf16 bf16x8 __attribute__((ext_vector_type(8)));
typedef float floatx4 __attribute__((ext_vector_type(4)));

__device__ __forceinline__ float b2f(bf16 v) { return __bfloat162float(v); }
__device__ __forceinline__ bf16 f2b(float v) { return __float2bfloat16(v); }
__device__ __forceinline__ ushort f2bu(float v) { bf16 h = __float2bfloat16(v); return *(ushort*)&h; }
__device__ __forceinline__ float ldf(const void* p, size_t i, int isbf) {
    return isbf ? __bfloat162float(((const bf16*)p)[i]) : ((const float*)p)[i];
}

// ---------------- input dtype probe ----------------------------------------------
__global__ void detect_kernel(const unsigned int* __restrict__ x, int* __restrict__ flag) {
    if (threadIdx.x == 0 && blockIdx.x == 0) {
        int cnt = 0;
        for (int i = 0; i < 64; i++) {
            unsigned int e = (x[i] >> 7) & 0xFFu;
            if (e >= 100u && e <= 140u) cnt++;
        }
        *flag = (cnt >= 48) ? 1 : 0;
    }
}

// ---------------- weight convert: 3 segments -> contiguous bf16 ------------------
__global__ void wconv_kernel(const void* __restrict__ w0, const void* __restrict__ w1,
                             const void* __restrict__ w2, bf16* __restrict__ dst,
                             const int* __restrict__ flagp) {
    int isbf = *flagp;
    const int n0 = INNER * CIN, n1 = 2 * INNER * CIN, n2 = INNER * CIN;
    int i = blockIdx.x * 256 + threadIdx.x;
    int total = n0 + n1 + n2;
    for (; i < total; i += gridDim.x * 256) {
        float v;
        if (i < n0) v = ldf(w0, i, isbf);
        else if (i < n0 + n1) v = ldf(w1, i - n0, isbf);
        else v = ldf(w2, i - n0 - n1, isbf);
        dst[i] = f2b(v);
    }
}

// ---------------- depthwise 3x3 + BN, writes Y^T [b][p][c] -----------------------
template <int STRIDE, int HO, int WO>
__global__ void dw_bn_kernel(const void* __restrict__ x, const void* __restrict__ wdw,
                             const void* __restrict__ gamma, const void* __restrict__ beta,
                             const void* __restrict__ mean, const void* __restrict__ var,
                             bf16* __restrict__ yt, const int* __restrict__ flagp) {
    __shared__ float xs[32][33];
    int isbf = *flagp;
    int bc = blockIdx.x;
    int c = bc % CIN;
    int b = bc / CIN;
    int tid = threadIdx.x;
    size_t xbase = (size_t)bc * (32 * 32);
    for (int i = tid; i < 32 * 32; i += 256)
        xs[i >> 5][i & 31] = ldf(x, xbase + i, isbf);
    float w[9];
#pragma unroll
    for (int k = 0; k < 9; k++) w[k] = ldf(wdw, c * 9 + k, isbf);
    float inv = ldf(gamma, c, isbf) * rsqrtf(ldf(var, c, isbf) + 1e-5f);
    float bias = ldf(beta, c, isbf) - ldf(mean, c, isbf) * inv;
    __syncthreads();
    for (int p = tid; p < HO * WO; p += 256) {
        int ho = p / WO, wo = p % WO;
        int ci = ho * STRIDE, cj = wo * STRIDE;
        float acc = 0.f;
#pragma unroll
        for (int ky = 0; ky < 3; ky++) {
            int yy = ci + ky - 1;
            if (yy < 0 || yy >= 32) continue;
#pragma unroll
            for (int kx = 0; kx < 3; kx++) {
                int xx = cj + kx - 1;
                if (xx < 0 || xx >= 32) continue;
                acc += w[ky * 3 + kx] * xs[yy][xx];
            }
        }
        yt[((size_t)b * (HO * WO) + p) * CIN + c] = f2b(acc * inv + bias);
    }
}

// ---------------- MFMA pointwise GEMM --------------------------------------------
// C^T[p][o] = sum_c Yt[b][p][c] * W[o][c].  A = Yt rows, B = W rows: both
// contiguous-in-c -> direct global bf16x8 frag loads, no LDS.
// MODE 0: store per-head  out[((b*6 + o/64)*P + p)*64 + (o&63)]      (Q or K alone)
// MODE 1: o<384 -> per-head kalt (P=PKV); o>=384 -> valt[b][o-384][p] (K|V fused)
// MODE 2: final out[b][o][P] + bias, dtype per flag
template <int P, int MODE>
__global__ __launch_bounds__(256, 1) void mfma_pw(
        const bf16* __restrict__ wt, const bf16* __restrict__ yt,
        const void* __restrict__ bias, void* __restrict__ out0,
        bf16* __restrict__ out1, int O, const int* __restrict__ flagp) {
    int tid = threadIdx.x;
    int wave = tid >> 6, lane = tid & 63;
    int l15 = lane & 15, quad = lane >> 4;
    int wm = wave & 1, wn = wave >> 1;
    int b = blockIdx.z;
    int p0 = blockIdx.x * 128 + wm * 64;
    int o0 = blockIdx.y * 128 + wn * 64;

    const bf16* ybase = yt + (size_t)b * P * CIN;
    const bf16* arow[4];
    const bf16* brow[4];
#pragma unroll
    for (int pt = 0; pt < 4; pt++) arow[pt] = ybase + (size_t)(p0 + pt * 16 + l15) * CIN + quad * 8;
#pragma unroll
    for (int ot = 0; ot < 4; ot++) brow[ot] = wt + (size_t)(o0 + ot * 16 + l15) * CIN + quad * 8;

    floatx4 acc[4][4];
#pragma unroll
    for (int pt = 0; pt < 4; pt++)
#pragma unroll
        for (int ot = 0; ot < 4; ot++) acc[pt][ot] = (floatx4){0.f, 0.f, 0.f, 0.f};

#pragma unroll
    for (int k = 0; k < CIN; k += 32) {
        bf16x8 af[4], bw[4];
#pragma unroll
        for (int pt = 0; pt < 4; pt++) af[pt] = *(const bf16x8*)(arow[pt] + k);
#pragma unroll
        for (int ot = 0; ot < 4; ot++) bw[ot] = *(const bf16x8*)(brow[ot] + k);
#pragma unroll
        for (int pt = 0; pt < 4; pt++)
#pragma unroll
            for (int ot = 0; ot < 4; ot++)
                acc[pt][ot] = __builtin_amdgcn_mfma_f32_16x16x32_bf16(af[pt], bw[ot], acc[pt][ot], 0, 0, 0);
    }

    if (MODE == 2) {
        int isbf = *flagp;
#pragma unroll
        for (int ot = 0; ot < 4; ot++) {
            int o = o0 + ot * 16 + l15;
            float bv = ldf(bias, o, isbf);
#pragma unroll
            for (int pt = 0; pt < 4; pt++) {
                int p = p0 + pt * 16 + quad * 4;
                size_t idx = ((size_t)b * O + o) * P + p;
                if (!isbf) {
                    float4 v4 = {acc[pt][ot][0] + bv, acc[pt][ot][1] + bv,
                                 acc[pt][ot][2] + bv, acc[pt][ot][3] + bv};
                    *(float4*)((float*)out0 + idx) = v4;
                } else {
                    ushort4 u4 = {f2bu(acc[pt][ot][0] + bv), f2bu(acc[pt][ot][1] + bv),
                                  f2bu(acc[pt][ot][2] + bv), f2bu(acc[pt][ot][3] + bv)};
                    *(ushort4*)((bf16*)out0 + idx) = u4;
                }
            }
        }
    } else if (MODE == 0) {
#pragma unroll
        for (int ot = 0; ot < 4; ot++) {
            int o = o0 + ot * 16 + l15;
            int h = o >> 6, d = o & 63;
            bf16* base = (bf16*)out0 + ((size_t)(b * HEADS + h) * P) * 64 + d;
#pragma unroll
            for (int pt = 0; pt < 4; pt++)
#pragma unroll
                for (int r = 0; r < 4; r++)
                    base[(size_t)(p0 + pt * 16 + quad * 4 + r) * 64] = f2b(acc[pt][ot][r]);
        }
    } else {  // MODE 1: K | V fused
#pragma unroll
        for (int ot = 0; ot < 4; ot++) {
            int o = o0 + ot * 16 + l15;
            if (o < INNER) {
                int h = o >> 6, d = o & 63;
                bf16* base = (bf16*)out0 + ((size_t)(b * HEADS + h) * P) * 64 + d;
#pragma unroll
                for (int pt = 0; pt < 4; pt++)
#pragma unroll
                    for (int r = 0; r < 4; r++)
                        base[(size_t)(p0 + pt * 16 + quad * 4 + r) * 64] = f2b(acc[pt][ot][r]);
            } else {
                int ch = o - INNER;
                bf16* base = out1 + ((size_t)b * INNER + ch) * P;
#pragma unroll
                for (int pt = 0; pt < 4; pt++)
#pragma unroll
                    for (int r = 0; r < 4; r++)
                        base[p0 + pt * 16 + quad * 4 + r] = f2b(acc[pt][ot][r]);
            }
        }
    }
}

// ---------------- fused MFMA attention -------------------------------------------
// out layout: ao[b][p][h*64+d]  (row-major in c, matching mfma_pw's A-operand)
__global__ __launch_bounds__(256, 1) void attn_kernel(
        const bf16* __restrict__ qalt, const bf16* __restrict__ kalt,
        const bf16* __restrict__ valt, bf16* __restrict__ ao) {
    __shared__ __align__(16) ushort Pl[4][16][264];
    __shared__ __align__(16) ushort Ot[4][16][80];  // O-tile transpose buffer
    int tid = threadIdx.x;
    int wave = tid >> 6, lane = tid & 63;
    int l15 = lane & 15, quad = lane >> 4;
    int blk = blockIdx.x;
    int b = blk / (HEADS * 16);
    int rem = blk % (HEADS * 16);
    int h = rem / 16;
    int p0 = (rem % 16) * 64 + wave * 16;

    const bf16* qbase = qalt + (size_t)(b * HEADS + h) * PQ * DH;
    const bf16* kbase = kalt + (size_t)(b * HEADS + h) * PKV * DH;
    const bf16* vbase = valt + ((size_t)b * INNER + h * DH) * PKV;

    const bf16* qrow = qbase + (size_t)(p0 + l15) * DH + quad * 8;
    bf16x8 a0 = *(const bf16x8*)qrow;
    bf16x8 a1 = *(const bf16x8*)(qrow + 32);

    floatx4 s[16];
#pragma unroll
    for (int jt = 0; jt < 16; jt++) s[jt] = (floatx4){0.f, 0.f, 0.f, 0.f};
#pragma unroll
    for (int jt = 0; jt < 16; jt++) {
        const bf16* krow = kbase + (size_t)(jt * 16 + l15) * DH + quad * 8;
        bf16x8 b0 = *(const bf16x8*)krow;
        bf16x8 b1 = *(const bf16x8*)(krow + 32);
        s[jt] = __builtin_amdgcn_mfma_f32_16x16x32_bf16(a0, b0, s[jt], 0, 0, 0);
        s[jt] = __builtin_amdgcn_mfma_f32_16x16x32_bf16(a1, b1, s[jt], 0, 0, 0);
    }

#pragma unroll
    for (int r = 0; r < 4; r++) {
        float mx = s[0][r];
#pragma unroll
        for (int jt = 1; jt < 16; jt++) mx = fmaxf(mx, s[jt][r]);
#pragma unroll
        for (int off = 1; off <= 8; off <<= 1) mx = fmaxf(mx, __shfl_xor(mx, off, 64));
        float sm = 0.f;
#pragma unroll
        for (int jt = 0; jt < 16; jt++) {
            float e = __expf((s[jt][r] - mx) * ATTN_SCALE);
            s[jt][r] = e;
            sm += e;
        }
#pragma unroll
        for (int off = 1; off <= 8; off <<= 1) sm += __shfl_xor(sm, off, 64);
        float inv = 1.f / sm;
#pragma unroll
        for (int jt = 0; jt < 16; jt++)
            Pl[wave][quad * 4 + r][jt * 16 + l15] = f2bu(s[jt][r] * inv);
    }
    __syncthreads();

    floatx4 oacc[4];
#pragma unroll
    for (int nt = 0; nt < 4; nt++) oacc[nt] = (floatx4){0.f, 0.f, 0.f, 0.f};
    bf16x8 pa[8];
#pragma unroll
    for (int kk = 0; kk < 8; kk++)
        pa[kk] = *(const bf16x8*)&Pl[wave][l15][kk * 32 + quad * 8];
#pragma unroll
    for (int nt = 0; nt < 4; nt++) {
#pragma unroll
        for (int kk = 0; kk < 8; kk++) {
            const bf16* vrow = vbase + (size_t)(nt * 16 + l15) * PKV + kk * 32 + quad * 8;
            bf16x8 bv = *(const bf16x8*)vrow;
            oacc[nt] = __builtin_amdgcn_mfma_f32_16x16x32_bf16(pa[kk], bv, oacc[nt], 0, 0, 0);
        }
    }

    // C-layout (row=p=quad*4+r, col=d=nt*16+l15) -> LDS -> coalesced [p][c] store
#pragma unroll
    for (int nt = 0; nt < 4; nt++)
#pragma unroll
        for (int r = 0; r < 4; r++)
            Ot[wave][quad * 4 + r][nt * 16 + l15] = f2bu(oacc[nt][r]);
    // wave-internal LDS RAW; compiler inserts lgkmcnt wait. No cross-wave sharing.
    int row = lane >> 2, d0 = (lane & 3) * 16;
    uint4 ld0 = *(const uint4*)&Ot[wave][row][d0];
    uint4 ld1 = *(const uint4*)&Ot[wave][row][d0 + 8];
    bf16* dst = ao + ((size_t)b * PQ + p0 + row) * INNER + h * DH + d0;
    *(uint4*)dst = ld0;
    *(uint4*)(dst + 8) = ld1;
}

extern "C" void kernel_launch(void* const* d_in, const int* in_sizes, int n_in,
                              void* d_out, int out_size, void* d_ws, size_t ws_size,
                              hipStream_t stream) {
    const void* x        = d_in[0];
    const void* q_dw     = d_in[1];
    const void* q_gamma  = d_in[2];
    const void* q_beta   = d_in[3];
    const void* q_mean   = d_in[4];
    const void* q_var    = d_in[5];
    const void* q_pw     = d_in[6];
    const void* kv_dw    = d_in[7];
    const void* kv_gamma = d_in[8];
    const void* kv_beta  = d_in[9];
    const void* kv_mean  = d_in[10];
    const void* kv_var   = d_in[11];
    const void* kv_pw    = d_in[12];
    const void* out_w    = d_in[13];
    const void* out_b    = d_in[14];

    int* flag = (int*)d_ws;
    bf16* pool = (bf16*)((char*)d_ws + 256);
    bf16* yqt  = pool;                              // [32,1024,384] Y^T Q-path; reused as aob
    bf16* ykvt = yqt  + (size_t)32 * 1024 * 384;    // [32,256,384]  Y^T KV-path
    bf16* qalt = ykvt + (size_t)32 * 256 * 384;     // [32,6,1024,64]
    bf16* kalt = qalt + (size_t)32 * 6 * 1024 * 64; // [32,6,256,64]
    bf16* valt = kalt + (size_t)32 * 6 * 256 * 64;  // [32,384,256]
    bf16* wbf  = valt + (size_t)32 * 384 * 256;     // q_pw | kv_pw | out_w bf16
    bf16* qpw_bf = wbf;
    bf16* kvpw_bf = wbf + (size_t)INNER * CIN;
    bf16* outw_bf = kvpw_bf + (size_t)2 * INNER * CIN;
    bf16* aob  = yqt;  // alias: yqt dead after Q pointwise; attn writes [b][p][c]

    detect_kernel<<<1, 64, 0, stream>>>((const unsigned int*)x, flag);
    wconv_kernel<<<576, 256, 0, stream>>>(q_pw, kv_pw, out_w, wbf, flag);
    dw_bn_kernel<1, 32, 32><<<32 * 384, 256, 0, stream>>>(x, q_dw, q_gamma, q_beta, q_mean, q_var, yqt, flag);
    dw_bn_kernel<2, 16, 16><<<32 * 384, 256, 0, stream>>>(x, kv_dw, kv_gamma, kv_beta, kv_mean, kv_var, ykvt, flag);
    mfma_pw<1024, 0><<<dim3(8, 3, 32), 256, 0, stream>>>(qpw_bf, yqt, nullptr, qalt, nullptr, INNER, flag);
    mfma_pw<256, 1><<<dim3(2, 6, 32), 256, 0, stream>>>(kvpw_bf, ykvt, nullptr, kalt, valt, 2 * INNER, flag);
    attn_kernel<<<32 * 6 * 16, 256, 0, stream>>>(qalt, kalt, valt, aob);
    mfma_pw<1024, 2><<<dim3(8, 3, 32), 256, 0, stream>>>(outw_bf, aob, out_b, d_out, nullptr, CIN, flag);
}

// Round 6
// 414.224 us; speedup vs baseline: 25.1800x; 1.0877x over previous
//
#include <hip/hip_runtime.h>
#include <hip/hip_bf16.h>

#define CIN 384
#define PQ 1024
#define PKV 256
#define HEADS 6
#define DH 64
#define INNER 384
#define ATTN_SCALE 0.125f

typedef __hip_bfloat16 bf16;
typedef unsigned short ushort;
typedef __bf16 bf16x8 __attribute__((ext_vector_type(8)));
typedef float floatx4 __attribute__((ext_vector_type(4)));

__device__ __forceinline__ float b2f(bf16 v) { return __bfloat162float(v); }
__device__ __forceinline__ bf16 f2b(float v) { return __float2bfloat16(v); }
__device__ __forceinline__ ushort f2bu(float v) { bf16 h = __float2bfloat16(v); return *(ushort*)&h; }
__device__ __forceinline__ float ldf(const void* p, size_t i, int isbf) {
    return isbf ? __bfloat162float(((const bf16*)p)[i]) : ((const float*)p)[i];
}

// ---------------- input dtype probe ----------------------------------------------
__global__ void detect_kernel(const unsigned int* __restrict__ x, int* __restrict__ flag) {
    if (threadIdx.x == 0 && blockIdx.x == 0) {
        int cnt = 0;
        for (int i = 0; i < 64; i++) {
            unsigned int e = (x[i] >> 7) & 0xFFu;
            if (e >= 100u && e <= 140u) cnt++;
        }
        *flag = (cnt >= 48) ? 1 : 0;
    }
}

// ---------------- weight convert: 3 segments -> contiguous bf16 ------------------
__global__ void wconv_kernel(const void* __restrict__ w0, const void* __restrict__ w1,
                             const void* __restrict__ w2, bf16* __restrict__ dst,
                             const int* __restrict__ flagp) {
    int isbf = *flagp;
    const int n0 = INNER * CIN, n1 = 2 * INNER * CIN, n2 = INNER * CIN;
    int i = blockIdx.x * 256 + threadIdx.x;
    int total = n0 + n1 + n2;
    for (; i < total; i += gridDim.x * 256) {
        float v;
        if (i < n0) v = ldf(w0, i, isbf);
        else if (i < n0 + n1) v = ldf(w1, i - n0, isbf);
        else v = ldf(w2, i - n0 - n1, isbf);
        dst[i] = f2b(v);
    }
}

// ---------------- depthwise 3x3 + BN -> Y^T [b][p][c], coalesced writes ----------
// Block = (rowgroup of 8 out-rows, 32-channel group, batch). x slab in LDS as
// [row][col][c] (pad 33): conflict-free fill (lane->col, stride 33) and
// conflict-free stencil reads (lane->c, contiguous). Store: 32 lanes cover 32
// consecutive c at one p -> full 64B lines, no write amplification.
template <int STRIDE, int HO, int WO>
__global__ __launch_bounds__(256) void dw_bn_kernel(
        const void* __restrict__ x, const void* __restrict__ wdw,
        const void* __restrict__ gamma, const void* __restrict__ beta,
        const void* __restrict__ mean, const void* __restrict__ var,
        bf16* __restrict__ yt, const int* __restrict__ flagp) {
    const int IN_ROWS = (8 - 1) * STRIDE + 3;
    __shared__ float xs[IN_ROWS][32][33];
    int isbf = *flagp;
    int rg = blockIdx.x;         // 8-out-row group
    int c0 = blockIdx.y * 32;    // channel group
    int b  = blockIdx.z;
    int tid = threadIdx.x;
    int ri0 = rg * 8 * STRIDE - 1;  // first input row of slab

    // fill slab: idx -> (i, cc, w); consecutive tid -> consecutive w (coalesced)
    for (int idx = tid; idx < IN_ROWS * 32 * 32; idx += 256) {
        int w_ = idx & 31;
        int cc = (idx >> 5) & 31;
        int i  = idx >> 10;
        int row = ri0 + i;
        float v = 0.f;
        if (row >= 0 && row < 32)
            v = ldf(x, ((size_t)(b * CIN + c0 + cc) * 32 + row) * 32 + w_, isbf);
        xs[i][w_][cc] = v;
    }

    int cc = tid & 31;           // channel within group
    int g  = tid >> 5;           // output row within group (0..7)
    int c  = c0 + cc;
    float w9[9];
#pragma unroll
    for (int k = 0; k < 9; k++) w9[k] = ldf(wdw, c * 9 + k, isbf);
    float inv = ldf(gamma, c, isbf) * rsqrtf(ldf(var, c, isbf) + 1e-5f);
    float bias = ldf(beta, c, isbf) - ldf(mean, c, isbf) * inv;
    __syncthreads();

    int orow = rg * 8 + g;
    bf16* orow_base = yt + ((size_t)b * (HO * WO) + (size_t)orow * WO) * CIN + c;
#pragma unroll
    for (int wo = 0; wo < WO; wo++) {
        float acc = 0.f;
#pragma unroll
        for (int ky = 0; ky < 3; ky++) {
#pragma unroll
            for (int kx = 0; kx < 3; kx++) {
                int ci = wo * STRIDE + kx - 1;
                if (ci < 0 || ci >= 32) continue;
                acc += w9[ky * 3 + kx] * xs[g * STRIDE + ky][ci][cc];
            }
        }
        orow_base[(size_t)wo * CIN] = f2b(acc * inv + bias);
    }
}

// ---------------- MFMA pointwise GEMM --------------------------------------------
// C^T[p][o] = sum_c Yt[b][p][c] * W[o][c].  A = Yt rows, B = W rows: both
// contiguous-in-c -> direct global bf16x8 frag loads, no LDS.
// MODE 0: store per-head  out[((b*6 + o/64)*P + p)*64 + (o&63)]      (Q or K alone)
// MODE 1: o<384 -> per-head kalt (P=PKV); o>=384 -> valt[b][o-384][p] (K|V fused)
// MODE 2: final out[b][o][P] + bias, dtype per flag
template <int P, int MODE>
__global__ __launch_bounds__(256, 1) void mfma_pw(
        const bf16* __restrict__ wt, const bf16* __restrict__ yt,
        const void* __restrict__ bias, void* __restrict__ out0,
        bf16* __restrict__ out1, int O, const int* __restrict__ flagp) {
    int tid = threadIdx.x;
    int wave = tid >> 6, lane = tid & 63;
    int l15 = lane & 15, quad = lane >> 4;
    int wm = wave & 1, wn = wave >> 1;
    int b = blockIdx.z;
    int p0 = blockIdx.x * 128 + wm * 64;
    int o0 = blockIdx.y * 128 + wn * 64;

    const bf16* ybase = yt + (size_t)b * P * CIN;
    const bf16* arow[4];
    const bf16* brow[4];
#pragma unroll
    for (int pt = 0; pt < 4; pt++) arow[pt] = ybase + (size_t)(p0 + pt * 16 + l15) * CIN + quad * 8;
#pragma unroll
    for (int ot = 0; ot < 4; ot++) brow[ot] = wt + (size_t)(o0 + ot * 16 + l15) * CIN + quad * 8;

    floatx4 acc[4][4];
#pragma unroll
    for (int pt = 0; pt < 4; pt++)
#pragma unroll
        for (int ot = 0; ot < 4; ot++) acc[pt][ot] = (floatx4){0.f, 0.f, 0.f, 0.f};

#pragma unroll
    for (int k = 0; k < CIN; k += 32) {
        bf16x8 af[4], bw[4];
#pragma unroll
        for (int pt = 0; pt < 4; pt++) af[pt] = *(const bf16x8*)(arow[pt] + k);
#pragma unroll
        for (int ot = 0; ot < 4; ot++) bw[ot] = *(const bf16x8*)(brow[ot] + k);
#pragma unroll
        for (int pt = 0; pt < 4; pt++)
#pragma unroll
            for (int ot = 0; ot < 4; ot++)
                acc[pt][ot] = __builtin_amdgcn_mfma_f32_16x16x32_bf16(af[pt], bw[ot], acc[pt][ot], 0, 0, 0);
    }

    if (MODE == 2) {
        int isbf = *flagp;
#pragma unroll
        for (int ot = 0; ot < 4; ot++) {
            int o = o0 + ot * 16 + l15;
            float bv = ldf(bias, o, isbf);
#pragma unroll
            for (int pt = 0; pt < 4; pt++) {
                int p = p0 + pt * 16 + quad * 4;
                size_t idx = ((size_t)b * O + o) * P + p;
                if (!isbf) {
                    float4 v4 = {acc[pt][ot][0] + bv, acc[pt][ot][1] + bv,
                                 acc[pt][ot][2] + bv, acc[pt][ot][3] + bv};
                    *(float4*)((float*)out0 + idx) = v4;
                } else {
                    ushort4 u4 = {f2bu(acc[pt][ot][0] + bv), f2bu(acc[pt][ot][1] + bv),
                                  f2bu(acc[pt][ot][2] + bv), f2bu(acc[pt][ot][3] + bv)};
                    *(ushort4*)((bf16*)out0 + idx) = u4;
                }
            }
        }
    } else if (MODE == 0) {
#pragma unroll
        for (int ot = 0; ot < 4; ot++) {
            int o = o0 + ot * 16 + l15;
            int h = o >> 6, d = o & 63;
            bf16* base = (bf16*)out0 + ((size_t)(b * HEADS + h) * P) * 64 + d;
#pragma unroll
            for (int pt = 0; pt < 4; pt++)
#pragma unroll
                for (int r = 0; r < 4; r++)
                    base[(size_t)(p0 + pt * 16 + quad * 4 + r) * 64] = f2b(acc[pt][ot][r]);
        }
    } else {  // MODE 1: K | V fused
#pragma unroll
        for (int ot = 0; ot < 4; ot++) {
            int o = o0 + ot * 16 + l15;
            if (o < INNER) {
                int h = o >> 6, d = o & 63;
                bf16* base = (bf16*)out0 + ((size_t)(b * HEADS + h) * P) * 64 + d;
#pragma unroll
                for (int pt = 0; pt < 4; pt++)
#pragma unroll
                    for (int r = 0; r < 4; r++)
                        base[(size_t)(p0 + pt * 16 + quad * 4 + r) * 64] = f2b(acc[pt][ot][r]);
            } else {
                int ch = o - INNER;
                bf16* base = out1 + ((size_t)b * INNER + ch) * P;
#pragma unroll
                for (int pt = 0; pt < 4; pt++)
#pragma unroll
                    for (int r = 0; r < 4; r++)
                        base[p0 + pt * 16 + quad * 4 + r] = f2b(acc[pt][ot][r]);
            }
        }
    }
}

// ---------------- fused MFMA attention -------------------------------------------
// out layout: ao[b][p][h*64+d]  (row-major in c, matching mfma_pw's A-operand)
__global__ __launch_bounds__(256, 1) void attn_kernel(
        const bf16* __restrict__ qalt, const bf16* __restrict__ kalt,
        const bf16* __restrict__ valt, bf16* __restrict__ ao) {
    __shared__ __align__(16) ushort Pl[4][16][264];
    __shared__ __align__(16) ushort Ot[4][16][80];  // O-tile transpose buffer
    int tid = threadIdx.x;
    int wave = tid >> 6, lane = tid & 63;
    int l15 = lane & 15, quad = lane >> 4;
    int blk = blockIdx.x;
    int b = blk / (HEADS * 16);
    int rem = blk % (HEADS * 16);
    int h = rem / 16;
    int p0 = (rem % 16) * 64 + wave * 16;

    const bf16* qbase = qalt + (size_t)(b * HEADS + h) * PQ * DH;
    const bf16* kbase = kalt + (size_t)(b * HEADS + h) * PKV * DH;
    const bf16* vbase = valt + ((size_t)b * INNER + h * DH) * PKV;

    const bf16* qrow = qbase + (size_t)(p0 + l15) * DH + quad * 8;
    bf16x8 a0 = *(const bf16x8*)qrow;
    bf16x8 a1 = *(const bf16x8*)(qrow + 32);

    floatx4 s[16];
#pragma unroll
    for (int jt = 0; jt < 16; jt++) s[jt] = (floatx4){0.f, 0.f, 0.f, 0.f};
#pragma unroll
    for (int jt = 0; jt < 16; jt++) {
        const bf16* krow = kbase + (size_t)(jt * 16 + l15) * DH + quad * 8;
        bf16x8 b0 = *(const bf16x8*)krow;
        bf16x8 b1 = *(const bf16x8*)(krow + 32);
        s[jt] = __builtin_amdgcn_mfma_f32_16x16x32_bf16(a0, b0, s[jt], 0, 0, 0);
        s[jt] = __builtin_amdgcn_mfma_f32_16x16x32_bf16(a1, b1, s[jt], 0, 0, 0);
    }

#pragma unroll
    for (int r = 0; r < 4; r++) {
        float mx = s[0][r];
#pragma unroll
        for (int jt = 1; jt < 16; jt++) mx = fmaxf(mx, s[jt][r]);
#pragma unroll
        for (int off = 1; off <= 8; off <<= 1) mx = fmaxf(mx, __shfl_xor(mx, off, 64));
        float sm = 0.f;
#pragma unroll
        for (int jt = 0; jt < 16; jt++) {
            float e = __expf((s[jt][r] - mx) * ATTN_SCALE);
            s[jt][r] = e;
            sm += e;
        }
#pragma unroll
        for (int off = 1; off <= 8; off <<= 1) sm += __shfl_xor(sm, off, 64);
        float inv = 1.f / sm;
#pragma unroll
        for (int jt = 0; jt < 16; jt++)
            Pl[wave][quad * 4 + r][jt * 16 + l15] = f2bu(s[jt][r] * inv);
    }
    __syncthreads();

    floatx4 oacc[4];
#pragma unroll
    for (int nt = 0; nt < 4; nt++) oacc[nt] = (floatx4){0.f, 0.f, 0.f, 0.f};
    bf16x8 pa[8];
#pragma unroll
    for (int kk = 0; kk < 8; kk++)
        pa[kk] = *(const bf16x8*)&Pl[wave][l15][kk * 32 + quad * 8];
#pragma unroll
    for (int nt = 0; nt < 4; nt++) {
#pragma unroll
        for (int kk = 0; kk < 8; kk++) {
            const bf16* vrow = vbase + (size_t)(nt * 16 + l15) * PKV + kk * 32 + quad * 8;
            bf16x8 bv = *(const bf16x8*)vrow;
            oacc[nt] = __builtin_amdgcn_mfma_f32_16x16x32_bf16(pa[kk], bv, oacc[nt], 0, 0, 0);
        }
    }

    // C-layout (row=p=quad*4+r, col=d=nt*16+l15) -> LDS -> coalesced [p][c] store
#pragma unroll
    for (int nt = 0; nt < 4; nt++)
#pragma unroll
        for (int r = 0; r < 4; r++)
            Ot[wave][quad * 4 + r][nt * 16 + l15] = f2bu(oacc[nt][r]);
    int row = lane >> 2, d0 = (lane & 3) * 16;
    uint4 ld0 = *(const uint4*)&Ot[wave][row][d0];
    uint4 ld1 = *(const uint4*)&Ot[wave][row][d0 + 8];
    bf16* dst = ao + ((size_t)b * PQ + p0 + row) * INNER + h * DH + d0;
    *(uint4*)dst = ld0;
    *(uint4*)(dst + 8) = ld1;
}

extern "C" void kernel_launch(void* const* d_in, const int* in_sizes, int n_in,
                              void* d_out, int out_size, void* d_ws, size_t ws_size,
                              hipStream_t stream) {
    const void* x        = d_in[0];
    const void* q_dw     = d_in[1];
    const void* q_gamma  = d_in[2];
    const void* q_beta   = d_in[3];
    const void* q_mean   = d_in[4];
    const void* q_var    = d_in[5];
    const void* q_pw     = d_in[6];
    const void* kv_dw    = d_in[7];
    const void* kv_gamma = d_in[8];
    const void* kv_beta  = d_in[9];
    const void* kv_mean  = d_in[10];
    const void* kv_var   = d_in[11];
    const void* kv_pw    = d_in[12];
    const void* out_w    = d_in[13];
    const void* out_b    = d_in[14];

    int* flag = (int*)d_ws;
    bf16* pool = (bf16*)((char*)d_ws + 256);
    bf16* yqt  = pool;                              // [32,1024,384] Y^T Q-path; reused as aob
    bf16* ykvt = yqt  + (size_t)32 * 1024 * 384;    // [32,256,384]  Y^T KV-path
    bf16* qalt = ykvt + (size_t)32 * 256 * 384;     // [32,6,1024,64]
    bf16* kalt = qalt + (size_t)32 * 6 * 1024 * 64; // [32,6,256,64]
    bf16* valt = kalt + (size_t)32 * 6 * 256 * 64;  // [32,384,256]
    bf16* wbf  = valt + (size_t)32 * 384 * 256;     // q_pw | kv_pw | out_w bf16
    bf16* qpw_bf = wbf;
    bf16* kvpw_bf = wbf + (size_t)INNER * CIN;
    bf16* outw_bf = kvpw_bf + (size_t)2 * INNER * CIN;
    bf16* aob  = yqt;  // alias: yqt dead after Q pointwise; attn writes [b][p][c]

    detect_kernel<<<1, 64, 0, stream>>>((const unsigned int*)x, flag);
    wconv_kernel<<<576, 256, 0, stream>>>(q_pw, kv_pw, out_w, wbf, flag);
    dw_bn_kernel<1, 32, 32><<<dim3(4, 12, 32), 256, 0, stream>>>(x, q_dw, q_gamma, q_beta, q_mean, q_var, yqt, flag);
    dw_bn_kernel<2, 16, 16><<<dim3(2, 12, 32), 256, 0, stream>>>(x, kv_dw, kv_gamma, kv_beta, kv_mean, kv_var, ykvt, flag);
    mfma_pw<1024, 0><<<dim3(8, 3, 32), 256, 0, stream>>>(qpw_bf, yqt, nullptr, qalt, nullptr, INNER, flag);
    mfma_pw<256, 1><<<dim3(2, 6, 32), 256, 0, stream>>>(kvpw_bf, ykvt, nullptr, kalt, valt, 2 * INNER, flag);
    attn_kernel<<<32 * 6 * 16, 256, 0, stream>>>(qalt, kalt, valt, aob);
    mfma_pw<1024, 2><<<dim3(8, 3, 32), 256, 0, stream>>>(outw_bf, aob, out_b, d_out, nullptr, CIN, flag);
}